// Round 3
// baseline (3531.076 us; speedup 1.0000x reference)
//
#include <hip/hip_runtime.h>

#define NH   4096
#define OBS  512
#define TPTS 64
#define LAT2 128
#define COMB (OBS + NH)

// k_out = tanh(Wf @ (h + afrac*dt*k_in) + bf)
// grid: NH/4 blocks of 256 threads; one row per wave.
__global__ __launch_bounds__(256) void ode_eval(
    const float* __restrict__ Wf, const float* __restrict__ bf,
    const float* __restrict__ h, const float* __restrict__ k_in,
    const float* __restrict__ t, int step, float afrac,
    float* __restrict__ k_out)
{
    __shared__ float vec[NH];
    const int tid = threadIdx.x;
    const float dt = t[step + 1] - t[step];
    const float a = afrac * dt;

    if (k_in) {
        for (int i = tid * 4; i < NH; i += 1024) {
            float4 hv = *reinterpret_cast<const float4*>(h + i);
            float4 kv = *reinterpret_cast<const float4*>(k_in + i);
            vec[i + 0] = hv.x + a * kv.x;
            vec[i + 1] = hv.y + a * kv.y;
            vec[i + 2] = hv.z + a * kv.z;
            vec[i + 3] = hv.w + a * kv.w;
        }
    } else {
        for (int i = tid * 4; i < NH; i += 1024) {
            *reinterpret_cast<float4*>(vec + i) =
                *reinterpret_cast<const float4*>(h + i);
        }
    }
    __syncthreads();

    const int wave = tid >> 6, lane = tid & 63;
    const int row = blockIdx.x * 4 + wave;
    const float* wrow = Wf + (size_t)row * NH;
    float acc = 0.f;
    for (int c = lane * 4; c < NH; c += 256) {
        float4 w = *reinterpret_cast<const float4*>(wrow + c);
        float4 v = *reinterpret_cast<const float4*>(vec + c);
        acc += w.x * v.x + w.y * v.y + w.z * v.z + w.w * v.w;
    }
    for (int o = 32; o > 0; o >>= 1) acc += __shfl_down(acc, o);
    if (lane == 0) k_out[row] = tanhf(acc + bf[row]);
}

// k4 = tanh(Wf @ (h + dt*k3) + bf);  h_out = h + dt/6*(k1 + 2k2 + 2k3 + k4)
__global__ __launch_bounds__(256) void ode_final(
    const float* __restrict__ Wf, const float* __restrict__ bf,
    const float* __restrict__ h, const float* __restrict__ k1,
    const float* __restrict__ k2, const float* __restrict__ k3,
    const float* __restrict__ t, int step,
    float* __restrict__ h_out)
{
    __shared__ float vec[NH];
    const int tid = threadIdx.x;
    const float dt = t[step + 1] - t[step];

    for (int i = tid * 4; i < NH; i += 1024) {
        float4 hv = *reinterpret_cast<const float4*>(h + i);
        float4 kv = *reinterpret_cast<const float4*>(k3 + i);
        vec[i + 0] = hv.x + dt * kv.x;
        vec[i + 1] = hv.y + dt * kv.y;
        vec[i + 2] = hv.z + dt * kv.z;
        vec[i + 3] = hv.w + dt * kv.w;
    }
    __syncthreads();

    const int wave = tid >> 6, lane = tid & 63;
    const int row = blockIdx.x * 4 + wave;
    const float* wrow = Wf + (size_t)row * NH;
    float acc = 0.f;
    for (int c = lane * 4; c < NH; c += 256) {
        float4 w = *reinterpret_cast<const float4*>(wrow + c);
        float4 v = *reinterpret_cast<const float4*>(vec + c);
        acc += w.x * v.x + w.y * v.y + w.z * v.z + w.w * v.w;
    }
    for (int o = 32; o > 0; o >>= 1) acc += __shfl_down(acc, o);
    if (lane == 0) {
        float k4 = tanhf(acc + bf[row]);
        h_out[row] = h[row] + (dt / 6.f) *
                     (k1[row] + 2.f * k2[row] + 2.f * k3[row] + k4);
    }
}

// out[row] = tanh(W_i2h[row] @ [x; hT] + b_i2h[row]);  rows = NH
__global__ __launch_bounds__(256) void i2h_kernel(
    const float* __restrict__ W, const float* __restrict__ b,
    const float* __restrict__ x, const float* __restrict__ hT,
    float* __restrict__ out)
{
    __shared__ float vec[COMB];
    const int tid = threadIdx.x;
    for (int i = tid * 4; i < COMB; i += 1024) {
        float4 v;
        if (i < OBS) v = *reinterpret_cast<const float4*>(x + i);
        else         v = *reinterpret_cast<const float4*>(hT + (i - OBS));
        *reinterpret_cast<float4*>(vec + i) = v;
    }
    __syncthreads();

    const int wave = tid >> 6, lane = tid & 63;
    const int row = blockIdx.x * 4 + wave;
    const float* wrow = W + (size_t)row * COMB;
    float acc = 0.f;
    for (int c = lane * 4; c < COMB; c += 256) {
        float4 w = *reinterpret_cast<const float4*>(wrow + c);
        float4 v = *reinterpret_cast<const float4*>(vec + c);
        acc += w.x * v.x + w.y * v.y + w.z * v.z + w.w * v.w;
    }
    for (int o = 32; o > 0; o >>= 1) acc += __shfl_down(acc, o);
    if (lane == 0) out[row] = tanhf(acc + b[row]);
}

// out[row] = W_h2o[row] @ hn + b_h2o[row];  rows = 128
__global__ __launch_bounds__(256) void h2o_kernel(
    const float* __restrict__ W, const float* __restrict__ b,
    const float* __restrict__ hn, float* __restrict__ out)
{
    __shared__ float vec[NH];
    const int tid = threadIdx.x;
    for (int i = tid * 4; i < NH; i += 1024)
        *reinterpret_cast<float4*>(vec + i) =
            *reinterpret_cast<const float4*>(hn + i);
    __syncthreads();

    const int wave = tid >> 6, lane = tid & 63;
    const int row = blockIdx.x * 4 + wave;
    const float* wrow = W + (size_t)row * NH;
    float acc = 0.f;
    for (int c = lane * 4; c < NH; c += 256) {
        float4 w = *reinterpret_cast<const float4*>(wrow + c);
        float4 v = *reinterpret_cast<const float4*>(vec + c);
        acc += w.x * v.x + w.y * v.y + w.z * v.z + w.w * v.w;
    }
    for (int o = 32; o > 0; o >>= 1) acc += __shfl_down(acc, o);
    if (lane == 0) out[row] = acc + b[row];
}

extern "C" void kernel_launch(void* const* d_in, const int* in_sizes, int n_in,
                              void* d_out, int out_size, void* d_ws, size_t ws_size,
                              hipStream_t stream)
{
    const float* x     = (const float*)d_in[0];
    const float* h0    = (const float*)d_in[1];
    const float* t     = (const float*)d_in[2];
    const float* Wf    = (const float*)d_in[3];
    const float* bf    = (const float*)d_in[4];
    const float* W_i2h = (const float*)d_in[5];
    const float* b_i2h = (const float*)d_in[6];
    const float* W_h2o = (const float*)d_in[7];
    const float* b_h2o = (const float*)d_in[8];
    float* out = (float*)d_out;

    float* ws = (float*)d_ws;
    float* hA = ws;
    float* hB = ws + NH;
    float* k1 = ws + 2 * NH;
    float* k2 = ws + 3 * NH;
    float* k3 = ws + 4 * NH;

    hipMemcpyAsync(hA, h0, NH * sizeof(float), hipMemcpyDeviceToDevice, stream);

    float* hcur = hA;
    float* hnxt = hB;
    const int grid = NH / 4;  // one row per wave, 4 waves per block
    for (int s = 0; s < TPTS - 1; ++s) {
        ode_eval<<<grid, 256, 0, stream>>>(Wf, bf, hcur, nullptr, t, s, 0.0f, k1);
        ode_eval<<<grid, 256, 0, stream>>>(Wf, bf, hcur, k1,      t, s, 0.5f, k2);
        ode_eval<<<grid, 256, 0, stream>>>(Wf, bf, hcur, k2,      t, s, 0.5f, k3);
        ode_final<<<grid, 256, 0, stream>>>(Wf, bf, hcur, k1, k2, k3, t, s, hnxt);
        float* tmp = hcur; hcur = hnxt; hnxt = tmp;
    }
    i2h_kernel<<<NH / 4, 256, 0, stream>>>(W_i2h, b_i2h, x, hcur, out + LAT2);
    h2o_kernel<<<LAT2 / 4, 256, 0, stream>>>(W_h2o, b_h2o, out + LAT2, out);
}